// Round 1
// baseline (20.924 us; speedup 1.0000x reference)
//
#include <hip/hip_runtime.h>

typedef float float4v __attribute__((ext_vector_type(4)));

// out[token*768 + d] = emb[x[token]*768 + d] * scale(d)
// scale(d) = w3 + (d<576)*w2 + (d<384)*w1 + (d<192)*w0
// Work in float4 units: 192 float4 per token; each float4 lies in one segment.
__global__ void mixed_embed_kernel(const int* __restrict__ x,
                                   const float* __restrict__ w,
                                   const float* __restrict__ emb,
                                   float* __restrict__ out,
                                   int n_vec) {
    // All threads read the same 4 floats -> L2/L1 broadcast, cheap.
    const float w0 = w[0], w1 = w[1], w2 = w[2], w3 = w[3];

    const int stride = gridDim.x * blockDim.x;
    for (int gid = blockIdx.x * blockDim.x + threadIdx.x; gid < n_vec; gid += stride) {
        const int token = gid / 192;          // magic-multiply, cheap
        const int d4    = gid - token * 192;  // float4 column index [0,192)
        const int row   = x[token];           // 192 consecutive lanes share this -> cached

        const float4v v = reinterpret_cast<const float4v*>(emb)[(long)row * 192 + d4];

        // Branchless piecewise-constant scale (no runtime-indexed array -> no scratch).
        float s = w3;
        s += (d4 < 144) ? w2 : 0.0f;   // d < 576
        s += (d4 <  96) ? w1 : 0.0f;   // d < 384
        s += (d4 <  48) ? w0 : 0.0f;   // d < 192

        float4v o = v;
        o[0] *= s; o[1] *= s; o[2] *= s; o[3] *= s;
        reinterpret_cast<float4v*>(out)[gid] = o;
    }
}

extern "C" void kernel_launch(void* const* d_in, const int* in_sizes, int n_in,
                              void* d_out, int out_size, void* d_ws, size_t ws_size,
                              hipStream_t stream) {
    const int*   x   = (const int*)d_in[0];    // [8*2048] token ids
    const float* w   = (const float*)d_in[1];  // [4] mixture weights
    const float* emb = (const float*)d_in[2];  // [50257*768]
    float*       out = (float*)d_out;          // [8*2048*768]

    const int n_vec = out_size / 4;            // float4 count = 3,145,728
    const int block = 256;
    int grid = (n_vec + block - 1) / block;
    if (grid > 2048) grid = 2048;              // grid-stride the rest

    mixed_embed_kernel<<<grid, block, 0, stream>>>(x, w, emb, out, n_vec);
}